// Round 4
// baseline (302.506 us; speedup 1.0000x reference)
//
#include <hip/hip_runtime.h>

#define DD 64
#define NN 512
#define BB 4
#define NEG_SLOPE 0.01f

typedef float floatx4 __attribute__((ext_vector_type(4)));

// ws layout (floats): cq[64], ck[64], cv[64], C (1)
__global__ void precompute_kernel(const float* __restrict__ W_w,
                                  const float* __restrict__ W_b,
                                  const float* __restrict__ a_w,
                                  const float* __restrict__ a_b,
                                  float* __restrict__ ws) {
    int d = threadIdx.x;  // 0..63
    float cq = 0.f, ck = 0.f, cv = 0.f;
    for (int e = 0; e < DD; ++e) {
        float w = W_w[e * DD + d];          // W_w[e,d], coalesced over d
        cq = fmaf(a_w[e], w, cq);
        ck = fmaf(a_w[DD + e], w, ck);
        cv = fmaf(a_w[2 * DD + e], w, cv);
    }
    ws[d] = cq;
    ws[DD + d] = ck;
    ws[2 * DD + d] = cv;
    // C = dot(W_b, a_q + a_k + a_v) + a_b[0]
    float p = W_b[d] * (a_w[d] + a_w[DD + d] + a_w[2 * DD + d]);
#pragma unroll
    for (int off = 32; off; off >>= 1) p += __shfl_down(p, off, 64);
    if (d == 0) ws[3 * DD] = p + a_b[0];
}

// Pure streaming writer: out_value[b,i,j,d] = e[b,i,d] * e[b,j,d].
// One block per (b,i) row; 256 threads; thread t: d4 = t&15, jl = t>>4.
// Each wave stores 1 KB contiguous per iteration; nontemporal (no reuse).
__global__ __launch_bounds__(256) void value_kernel(
        const float* __restrict__ emb,
        float* __restrict__ out_value) {
    const int row = blockIdx.x;      // b*NN + i
    const int b = row >> 9;
    const int t = threadIdx.x;
    const int d4 = t & 15;
    const int jl = t >> 4;

    const floatx4* emb4 = (const floatx4*)emb;
    const floatx4 ei = emb4[(size_t)row * 16 + d4];
    const floatx4* embB = emb4 + (size_t)b * NN * 16;
    floatx4* val4 = (floatx4*)out_value + (size_t)row * NN * 16;

#pragma unroll 8
    for (int it = 0; it < NN / 16; ++it) {
        const int j = it * 16 + jl;
        const floatx4 ej = embB[j * 16 + d4];
        const floatx4 p = ei * ej;
        __builtin_nontemporal_store(p, &val4[j * 16 + d4]);
    }
}

// Alpha (softmax) kernel: s[b,i,j] = ei.cq + Σ_d ej[d]*(ei[d]*cv[d] + ck[d]) + C
// One block per (b,i) row; 256 threads; 16 lanes cooperate per j.
__global__ __launch_bounds__(256) void alpha_kernel(
        const float* __restrict__ emb,
        const float* __restrict__ ws,
        float* __restrict__ out_alpha) {
    const int row = blockIdx.x;
    const int b = row >> 9;
    const int t = threadIdx.x;
    const int d4 = t & 15;
    const int jl = t >> 4;

    __shared__ float s_lds[NN];
    __shared__ float red[8];

    const floatx4* emb4 = (const floatx4*)emb;
    const floatx4 ei = emb4[(size_t)row * 16 + d4];
    const floatx4 cq = ((const floatx4*)ws)[d4];
    const floatx4 ck = ((const floatx4*)(ws + DD))[d4];
    const floatx4 cv = ((const floatx4*)(ws + 2 * DD))[d4];
    const float Cc = ws[3 * DD];

    const floatx4* embB = emb4 + (size_t)b * NN * 16;

    // combined per-d coefficient: cvec[d] = ei[d]*cv[d] + ck[d]
    floatx4 cvec = ei * cv + ck;
    // partial of ei·cq (full dot emerges from the 16-lane reduction)
    const float pq = ei.x * cq.x + ei.y * cq.y + ei.z * cq.z + ei.w * cq.w;

#pragma unroll 4
    for (int it = 0; it < NN / 16; ++it) {
        const int j = it * 16 + jl;
        const floatx4 ej = embB[j * 16 + d4];
        float v = ej.x * cvec.x + ej.y * cvec.y + ej.z * cvec.z + ej.w * cvec.w + pq;
        v += __shfl_xor(v, 1, 64);
        v += __shfl_xor(v, 2, 64);
        v += __shfl_xor(v, 4, 64);
        v += __shfl_xor(v, 8, 64);
        if (d4 == 0) {
            float s = v + Cc;
            s_lds[j] = (s >= 0.f) ? s : NEG_SLOPE * s;     // leaky relu
        }
    }
    __syncthreads();

    // block softmax over 512 entries (each thread owns 2)
    float s0 = s_lds[t], s1 = s_lds[t + 256];
    float m = fmaxf(s0, s1);
#pragma unroll
    for (int off = 32; off; off >>= 1) m = fmaxf(m, __shfl_xor(m, off, 64));
    const int wid = t >> 6, lane = t & 63;
    if (lane == 0) red[wid] = m;
    __syncthreads();
    m = fmaxf(fmaxf(red[0], red[1]), fmaxf(red[2], red[3]));

    float e0 = expf(s0 - m), e1 = expf(s1 - m);
    float ps = e0 + e1;
#pragma unroll
    for (int off = 32; off; off >>= 1) ps += __shfl_xor(ps, off, 64);
    if (lane == 0) red[4 + wid] = ps;
    __syncthreads();
    const float inv = 1.f / (red[4] + red[5] + red[6] + red[7]);

    float* arow = out_alpha + (size_t)row * NN;
    arow[t] = e0 * inv;
    arow[t + 256] = e1 * inv;
}

extern "C" void kernel_launch(void* const* d_in, const int* in_sizes, int n_in,
                              void* d_out, int out_size, void* d_ws, size_t ws_size,
                              hipStream_t stream) {
    const float* emb = (const float*)d_in[0];
    const float* W_w = (const float*)d_in[1];
    const float* W_b = (const float*)d_in[2];
    const float* a_w = (const float*)d_in[3];
    const float* a_b = (const float*)d_in[4];
    float* ws = (float*)d_ws;

    float* out = (float*)d_out;
    float* out_alpha = out;                                  // B*N*N floats
    float* out_value = out + (size_t)BB * NN * NN;           // B*N*N*D floats

    value_kernel<<<BB * NN, 256, 0, stream>>>(emb, out_value);
    precompute_kernel<<<1, 64, 0, stream>>>(W_w, W_b, a_w, a_b, ws);
    alpha_kernel<<<BB * NN, 256, 0, stream>>>(emb, ws, out_alpha);
}

// Round 6
// 275.356 us; speedup vs baseline: 1.0986x; 1.0986x over previous
//
#include <hip/hip_runtime.h>

#define DD 64
#define NN 512
#define BB 4
#define NEG_SLOPE 0.01f

typedef float floatx4 __attribute__((ext_vector_type(4)));

// ws layout (floats): cq[64], ck[64], cv[64], C (1)
__global__ void precompute_kernel(const float* __restrict__ W_w,
                                  const float* __restrict__ W_b,
                                  const float* __restrict__ a_w,
                                  const float* __restrict__ a_b,
                                  float* __restrict__ ws) {
    int d = threadIdx.x;  // 0..63
    float cq = 0.f, ck = 0.f, cv = 0.f;
    for (int e = 0; e < DD; ++e) {
        float w = W_w[e * DD + d];          // W_w[e,d], coalesced over d
        cq = fmaf(a_w[e], w, cq);
        ck = fmaf(a_w[DD + e], w, ck);
        cv = fmaf(a_w[2 * DD + e], w, cv);
    }
    ws[d] = cq;
    ws[DD + d] = ck;
    ws[2 * DD + d] = cv;
    // C = dot(W_b, a_q + a_k + a_v) + a_b[0]
    float p = W_b[d] * (a_w[d] + a_w[DD + d] + a_w[2 * DD + d]);
#pragma unroll
    for (int off = 32; off; off >>= 1) p += __shfl_down(p, off, 64);
    if (d == 0) ws[3 * DD] = p + a_b[0];
}

// Fused: one block per (b,i) row; 256 threads; t -> d4 = t&15, jl = t>>4.
// Streaming loop: write value[b,i,j,:] (coalesced 1KB/wave-instr) and deposit
// per-thread 4-wide dot partials into LDS — NO cross-lane ops in the hot loop.
// Epilogue: thread t sums the 16 partials for rows t and t+256, then block softmax.
__global__ __launch_bounds__(256) void fused_kernel(
        const float* __restrict__ emb,
        const float* __restrict__ ws,
        float* __restrict__ out_alpha,
        float* __restrict__ out_value) {
    const int row = blockIdx.x;      // b*NN + i
    const int b = row >> 9;
    const int t = threadIdx.x;
    const int d4 = t & 15;
    const int jl = t >> 4;

    __shared__ float s_part[NN][17];   // stride 17: conflict-light partials
    __shared__ float red[8];

    const floatx4* emb4 = (const floatx4*)emb;
    const floatx4 ei = emb4[(size_t)row * 16 + d4];
    const floatx4 cq = ((const floatx4*)ws)[d4];
    const floatx4 ck = ((const floatx4*)(ws + DD))[d4];
    const floatx4 cv = ((const floatx4*)(ws + 2 * DD))[d4];
    const float Cc = ws[3 * DD];

    const floatx4* embB = emb4 + (size_t)b * NN * 16;
    floatx4* val4 = (floatx4*)out_value + (size_t)row * NN * 16;

    // cvec[d] = ei[d]*cv[d] + ck[d]; summing (ej.cvec + pq) over the 16 d4-lanes
    // of a j yields s_k + wv.a_v + s_q exactly.
    const floatx4 cvec = ei * cv + ck;
    const float pq = ei.x * cq.x + ei.y * cq.y + ei.z * cq.z + ei.w * cq.w;

#pragma unroll 8
    for (int it = 0; it < NN / 16; ++it) {
        const int j = it * 16 + jl;
        const floatx4 ej = embB[j * 16 + d4];
        const floatx4 p = ei * ej;
        val4[j * 16 + d4] = p;                              // value write
        s_part[j][d4] = ej.x * cvec.x + ej.y * cvec.y
                      + ej.z * cvec.z + ej.w * cvec.w + pq; // private partial
    }
    __syncthreads();

    // epilogue: sum 16 partials per j (thread t owns j = t and j = t+256)
    float s0 = 0.f, s1 = 0.f;
#pragma unroll
    for (int k = 0; k < 16; ++k) {
        s0 += s_part[t][k];
        s1 += s_part[t + 256][k];
    }
    s0 += Cc; s1 += Cc;
    s0 = (s0 >= 0.f) ? s0 : NEG_SLOPE * s0;                 // leaky relu
    s1 = (s1 >= 0.f) ? s1 : NEG_SLOPE * s1;

    // block softmax over 512 entries
    float m = fmaxf(s0, s1);
#pragma unroll
    for (int off = 32; off; off >>= 1) m = fmaxf(m, __shfl_xor(m, off, 64));
    const int wid = t >> 6, lane = t & 63;
    if (lane == 0) red[wid] = m;
    __syncthreads();
    m = fmaxf(fmaxf(red[0], red[1]), fmaxf(red[2], red[3]));

    float e0 = expf(s0 - m), e1 = expf(s1 - m);
    float ps = e0 + e1;
#pragma unroll
    for (int off = 32; off; off >>= 1) ps += __shfl_xor(ps, off, 64);
    if (lane == 0) red[4 + wid] = ps;
    __syncthreads();
    const float inv = 1.f / (red[4] + red[5] + red[6] + red[7]);

    float* arow = out_alpha + (size_t)row * NN;
    arow[t] = e0 * inv;
    arow[t + 256] = e1 * inv;
}

extern "C" void kernel_launch(void* const* d_in, const int* in_sizes, int n_in,
                              void* d_out, int out_size, void* d_ws, size_t ws_size,
                              hipStream_t stream) {
    const float* emb = (const float*)d_in[0];
    const float* W_w = (const float*)d_in[1];
    const float* W_b = (const float*)d_in[2];
    const float* a_w = (const float*)d_in[3];
    const float* a_b = (const float*)d_in[4];
    float* ws = (float*)d_ws;

    float* out = (float*)d_out;
    float* out_alpha = out;                                  // B*N*N floats
    float* out_value = out + (size_t)BB * NN * NN;           // B*N*N*D floats

    precompute_kernel<<<1, 64, 0, stream>>>(W_w, W_b, a_w, a_b, ws);
    fused_kernel<<<BB * NN, 256, 0, stream>>>(emb, ws, out_alpha, out_value);
}